// Round 6
// baseline (280.649 us; speedup 1.0000x reference)
//
#include <hip/hip_runtime.h>

// SoftDTW: B=16, T=1024, C=64, gamma=0.01, BIG=1e10
// out = sum_b softdtw(cost[b]) ; cost[b][i][j] = ||x[b,i]-y[b,j]||^2
//
// R6: decoupled systolic DP. 256 blocks x 64 threads (1 wave each); block
// (b,p) owns rows 64p+1..64p+64 of batch b and streams all 1024 columns
// continuously (1087 steps; fill/drain paid once, not per chunk). Inter-band
// handoff via global-memory boundary rows in 64-col windows with agent-scope
// flags (correct across XCDs; blockIdx swizzle makes neighbors same-XCD for
// speed). Cost remains the skewed layout: 1 coalesced 256B load/step,
// 64-deep double-buffered register prefetch (1 wave/CU -> VGPRs are free).

#define TT 1024
#define BB 16
#define CC 64
#define BIGV 1e10f
#define NW 16
#define NROWS (NW * TT)          // 16384 skew rows per batch (merged packing)
#define BNDROW 1152              // boundary row floats (1024 + overread pad)

// ---------------------------------------------------------------------------
// Kernel 1: cost tile 64x64 -> skewed coalesced store via LDS shear.
// cost = xn + yn + sum(-2x*y). R6: stride 65->68 (16B-aligned rows) and
// ds_read_b128 in the inner product (R5 was LDS-issue bound: 8 b32/k).
// ---------------------------------------------------------------------------
__global__ __launch_bounds__(256) void skew_cost_kernel(const float* __restrict__ x,
                                                        const float* __restrict__ y,
                                                        float* __restrict__ skew) {
    __shared__ __align__(16) float lds[2 * 64 * 68];   // 8704 floats; shear reuse
    __shared__ float xn[64], yn[64];
    float* xs = lds;                 // [64][68], pre-scaled by -2
    float* ys = lds + 64 * 68;       // [64][68]
    const int bx = blockIdx.x;       // column tile (j0 = 64*bx)
    const int by = blockIdx.y;       // band p     (i0 = 64*by)
    const int bz = blockIdx.z;       // batch
    const int tid = threadIdx.x;

    const float4* xg = (const float4*)(x + ((size_t)bz * TT + by * 64) * CC);
    const float4* yg = (const float4*)(y + ((size_t)bz * TT + bx * 64) * CC);
#pragma unroll
    for (int t = 0; t < 4; ++t) {
        int idx = t * 256 + tid;     // 0..1023
        int r = idx >> 4, f = idx & 15;
        float4 v = xg[r * 16 + f];
        xs[r * 68 + f * 4 + 0] = -2.0f * v.x; xs[r * 68 + f * 4 + 1] = -2.0f * v.y;
        xs[r * 68 + f * 4 + 2] = -2.0f * v.z; xs[r * 68 + f * 4 + 3] = -2.0f * v.w;
        float4 u = yg[r * 16 + f];
        ys[r * 68 + f * 4 + 0] = u.x; ys[r * 68 + f * 4 + 1] = u.y;
        ys[r * 68 + f * 4 + 2] = u.z; ys[r * 68 + f * 4 + 3] = u.w;
    }
    __syncthreads();

    if (tid < 128) {                 // row norms (b128 reads)
        int r = tid & 63;
        const float* row = (tid < 64) ? (xs + r * 68) : (ys + r * 68);
        float s = 0.f;
#pragma unroll
        for (int k4 = 0; k4 < 16; ++k4) {
            float4 v = *(const float4*)&row[4 * k4];
            s = fmaf(v.x, v.x, s); s = fmaf(v.y, v.y, s);
            s = fmaf(v.z, v.z, s); s = fmaf(v.w, v.w, s);
        }
        if (tid < 64) xn[r] = 0.25f * s; else yn[r] = s;
    }

    const int tr = tid >> 4, tc = tid & 15;
    float acc[4][4] = {};            // accumulates -2 * x.y
#pragma unroll 4
    for (int k4 = 0; k4 < 16; ++k4) {
        float4 xa4[4], yb4[4];
#pragma unroll
        for (int a = 0; a < 4; ++a) xa4[a] = *(const float4*)&xs[(4 * tr + a) * 68 + 4 * k4];
#pragma unroll
        for (int b = 0; b < 4; ++b) yb4[b] = *(const float4*)&ys[(4 * tc + b) * 68 + 4 * k4];
#pragma unroll
        for (int a = 0; a < 4; ++a)
#pragma unroll
            for (int b = 0; b < 4; ++b) {
                acc[a][b] = fmaf(xa4[a].x, yb4[b].x, acc[a][b]);
                acc[a][b] = fmaf(xa4[a].y, yb4[b].y, acc[a][b]);
                acc[a][b] = fmaf(xa4[a].z, yb4[b].z, acc[a][b]);
                acc[a][b] = fmaf(xa4[a].w, yb4[b].w, acc[a][b]);
            }
    }
    __syncthreads();                 // norms visible; stage area reusable

    float xnr[4], ynr[4];
#pragma unroll
    for (int a = 0; a < 4; ++a) { xnr[a] = xn[4 * tr + a]; ynr[a] = yn[4 * tc + a]; }

    // shear: sh[d][l], d = jl + l (0..126), stride 68 (max 126*68+63=8631 ok)
    float* sh = lds;
#pragma unroll
    for (int a = 0; a < 4; ++a)
#pragma unroll
        for (int b = 0; b < 4; ++b) {
            int l = 4 * tr + a, jl = 4 * tc + b;
            sh[(l + jl) * 68 + l] = acc[a][b] + xnr[a] + ynr[b];
        }
    __syncthreads();

    const int l = tid & 63, wv = tid >> 6;
    float* sb = skew + (size_t)bz * NROWS * 64;
    const int r0 = by * TT + bx * 64;
    for (int d = wv; d < 127; d += 4) {
        float v = sh[d * 68 + l];
        int lo = d - 63; lo = lo < 0 ? 0 : lo;
        int hi = d < 63 ? d : 63;
        int row = r0 + d; if (row >= NROWS) row -= NROWS;   // band-15 tail wrap
        if (l >= lo && l <= hi) sb[(size_t)row * 64 + l] = v;
    }
}

// lane l gets lane l-1's `cur`; lane 0 gets `lane0val` (via dpp old operand).
__device__ __forceinline__ float shift_up1(float cur, float lane0val) {
    int r = __builtin_amdgcn_update_dpp(__float_as_int(lane0val),
                                        __float_as_int(cur),
                                        0x138 /*WAVE_SHR1*/, 0xF, 0xF, false);
    return __int_as_float(r);
}

// ---------------------------------------------------------------------------
// Kernel 2: decoupled systolic DP. One 64-thread block per (batch, band).
// Lane l owns row 64p+l+1. 17 windows of 64 steps (last has 63).
// Step s computes col j = s-l+1; boundary Bnd[p][cb] = R[64(p+1)][cb+1],
// produced by lane63 at step cb+63, consumed by band p+1 lane0 at step cb.
// ---------------------------------------------------------------------------
__global__ __launch_bounds__(64) void dtw_pipe(const float* __restrict__ skew,
                                               float* __restrict__ bndg,
                                               int* __restrict__ flags,
                                               float* __restrict__ out) {
    __shared__ __align__(16) float bndlds[64];
    __shared__ float pubring[64];
    __shared__ float dump[64];
    const int bid = blockIdx.x;
    // XCD swizzle (perf only): all 16 bands of a batch on one XCD if the
    // mapping is round-robin; correctness never depends on it.
    const int grp = bid >> 3;
    const int p = grp & 15;                       // band
    const int b = ((grp >> 4) << 3) | (bid & 7);  // batch
    const int l = threadIdx.x;                    // lane 0..63

    const float* Dbat = skew + (size_t)b * NROWS * 64;
    float* BndOut = bndg + ((size_t)b * 16 + p) * BNDROW;
    float* BndIn  = bndg + ((size_t)b * 16 + (p > 0 ? p - 1 : 0)) * BNDROW;
    int* flagOut = flags + (b * 16 + p) * 16;
    int* flagIn  = flags + (b * 16 + (p > 0 ? p - 1 : 0)) * 16;
    const bool is_pub = (l == 63) && (p < 15);

    float cur  = BIGV;                              // R[i][j-1] carried
    float diag = (l == 0) ? ((p == 0) ? 0.0f : BIGV) : BIGV;  // R[i-1][j-1]
    bndlds[l] = BIGV;                               // stays BIG for p==0

    float qA[64], qB[64];
    auto loadq = [&](int Vn, float (&q)[64]) {      // cost rows for window Vn
        const int r0 = (p * TT + 64 * Vn) & (NROWS - 1);   // 64-aligned wrap
        const float* gp = Dbat + (size_t)r0 * 64 + l;
#pragma unroll
        for (int k = 0; k < 64; ++k) q[k] = gp[(size_t)k * 64];
    };

    auto bnd_fetch = [&](int V) {                   // flag wait + boundary->LDS
        if (p > 0) {
            if (l == 0) {
                while (__hip_atomic_load(&flagIn[V], __ATOMIC_RELAXED,
                                         __HIP_MEMORY_SCOPE_AGENT) == 0)
                    __builtin_amdgcn_s_sleep(1);
            }
            __builtin_amdgcn_fence(__ATOMIC_ACQUIRE, "agent");
            float rb = __hip_atomic_load(&BndIn[64 * V + l], __ATOMIC_RELAXED,
                                         __HIP_MEMORY_SCOPE_AGENT);
            bndlds[l] = rb;
        }
    };

    auto flush = [&](int W) {                       // publish window W + flag
        if (p < 15) {
            float fv = pubring[l];                  // slots 0..63 = cb 64W..64W+63
            __hip_atomic_store(&BndOut[64 * W + l], fv, __ATOMIC_RELAXED,
                               __HIP_MEMORY_SCOPE_AGENT);
            if (l == 0)
                __hip_atomic_store(&flagOut[W], 1, __ATOMIC_RELEASE,
                                   __HIP_MEMORY_SCOPE_AGENT);
        }
    };

    loadq(0, qA);

    // ---- window 0 (fill): steps s=0..63, act = (l <= s) -------------------
    {
        bnd_fetch(0);
        loadq(1, qB);
        const float* q = qA;
#pragma unroll
        for (int g = 0; g < 16; ++g) {
            float4 bqv = *(const float4*)&bndlds[4 * g];
            const float* bv = (const float*)&bqv;
#pragma unroll
            for (int kk = 0; kk < 4; ++kk) {
                const int k = 4 * g + kk;
                float up = shift_up1(cur, bv[kk]);
                float mn = fminf(fminf(up, cur), diag);
                float nv = q[k] + mn;
                bool act = (l <= k);
                cur = act ? nv : cur;
                diag = up;
                if (k == 63) {                      // cb=0 -> slot 0
                    float* dst = is_pub ? &pubring[0] : &dump[l];
                    *dst = cur;
                }
            }
        }
    }

    // ---- interior windows V=1..15: all lanes active -----------------------
    auto window_int = [&](int V, float (&q)[64], float (&qn)[64]) {
        bnd_fetch(V);
        loadq(V + 1, qn);
#pragma unroll
        for (int g = 0; g < 16; ++g) {
            float4 bqv = *(const float4*)&bndlds[4 * g];
            const float* bv = (const float*)&bqv;
#pragma unroll
            for (int kk = 0; kk < 4; ++kk) {
                const int k = 4 * g + kk;
                if (k == 63) flush(V - 1);          // window V-1 complete after k=62
                float up = shift_up1(cur, bv[kk]);
                float mn = fminf(fminf(up, cur), diag);
                cur = q[k] + mn;                    // all lanes active
                diag = up;
                // step k writes cb = 64V+k-63 -> slot (k+1)&63
                float* dst = is_pub ? &pubring[(k + 1) & 63] : &dump[l];
                *dst = cur;
            }
        }
    };

#pragma unroll 1
    for (int V = 1; V <= 13; V += 2) {
        window_int(V, qB, qA);
        window_int(V + 1, qA, qB);
    }
    window_int(15, qB, qA);                         // prefetches window 16 -> qA

    // ---- window 16 (drain): steps s=1024..1086, act = (l >= k+1) ----------
    {
        const float* q = qA;
#pragma unroll
        for (int k = 0; k < 63; ++k) {
            float up = shift_up1(cur, BIGV);        // lane0 inactive; old unused
            float mn = fminf(fminf(up, cur), diag);
            float nv = q[k] + mn;
            bool act = (l >= k + 1);
            cur = act ? nv : cur;
            diag = up;
            float* dst = is_pub ? &pubring[(k + 1) & 63] : &dump[l];
            *dst = cur;
        }
        flush(15);                                  // cb 960..1023
    }

    // band 15, lane 63 holds R[1024][1024]
    if (p == 15 && l == 63) atomicAdd(out, cur);
}

// ---------------------------------------------------------------------------
// Mid fallback (ws fits skew only): R5 barrier-tile DP (verified).
// ---------------------------------------------------------------------------
#define BROW 1024
#define BND_DUMMY_OFF (16 * BROW)
#define DUMP_OFF (17 * BROW)
#define BND_SIZE (17 * BROW + 256)

__global__ __launch_bounds__(1024, 4) void dtw_kernel(const float* __restrict__ skew,
                                                      float* __restrict__ out) {
    __shared__ float bnd[BND_SIZE];
    const int tid = threadIdx.x;
    const int l = tid & 63;
    const int w = __builtin_amdgcn_readfirstlane(tid >> 6);

    bnd[BND_DUMMY_OFF + tid] = BIGV;
    __syncthreads();

    const float* Dbat = skew + (size_t)blockIdx.x * NROWS * 64;
    const int bro = ((w == 0) ? 16 : (w - 1)) * BROW;
    const bool is_pub = (l == 63) && (w < NW - 1);
    const int Rw = w * TT;

    float cur  = BIGV;
    float diag = BIGV;

#pragma unroll 1
    for (int m = 0; m < 31; ++m) {
        const int c = m - w;
        if (c >= 0 && c < 16) {
            const int base = c * 64;
            float i0v = (base == 0) ? ((w == 0) ? 0.0f : BIGV)
                                    : bnd[bro + (base - 1)];
            diag = (l == 0) ? i0v : diag;
            float* pub = bnd + (is_pub ? (w * BROW - 63 + base) : (DUMP_OFF + l - 63));
            const int R0 = Rw + base;
            float cq[3][16];
            float4 bq[2][4];
            auto loadc = [&](int g, float (&q)[16]) {
                int r0 = R0 + 16 * g;
                if (r0 >= NROWS) r0 -= NROWS;
                const float* gb = Dbat + (size_t)r0 * 64;
#pragma unroll
                for (int k = 0; k < 16; ++k) q[k] = gb[l + 64 * k];
            };
            auto loadb = [&](int g, float4 (&bb)[4]) {
                const float4* bp = (const float4*)(bnd + bro + base + 16 * g);
#pragma unroll
                for (int k = 0; k < 4; ++k) bb[k] = bp[k];
            };
            loadc(0, cq[0]); loadc(1, cq[1]);
            loadb(0, bq[0]);
#pragma unroll
            for (int g = 0; g < 8; ++g) {
                if (g + 2 < 8) loadc(g + 2, cq[(g + 2) % 3]);
                if (g + 1 < 8) loadb(g + 1, bq[(g + 1) & 1]);
                const float* q  = cq[g % 3];
                const float* bv = (const float*)bq[g & 1];
#pragma unroll
                for (int k = 0; k < 16; ++k) {
                    const int s = 16 * g + k;
                    float up = shift_up1(cur, bv[k]);
                    float mn = fminf(fminf(up, cur), diag);
                    float nv = q[k] + mn;
                    bool act = (s < 64) ? (l <= s) : (l >= s - 63);
                    cur = act ? nv : cur;
                    diag = up;
                    if (s >= 63) pub[s] = cur;
                }
            }
        }
        __syncthreads();
    }
    if (tid == 1023) atomicAdd(out, cur);
}

// ---------------------------------------------------------------------------
// Last-resort fallback: naive fused DP.
// ---------------------------------------------------------------------------
__device__ __forceinline__ float softmin3(float a, float b, float c) {
    float m = fminf(fminf(a, b), c);
    float s = expf((m - a) * 100.0f) + expf((m - b) * 100.0f) + expf((m - c) * 100.0f);
    return m - 0.01f * logf(s);
}

__global__ __launch_bounds__(1024) void dtw_fly_kernel(const float* __restrict__ x,
                                                       const float* __restrict__ y,
                                                       float* __restrict__ out) {
    __shared__ float rbuf[3][TT + 1];
    const int b = blockIdx.x;
    const int t = threadIdx.x;

    float4 xr[16];
    const float4* xrow = (const float4*)(x + ((size_t)b * TT + t) * CC);
#pragma unroll
    for (int q = 0; q < 16; ++q) xr[q] = xrow[q];

    rbuf[0][t] = (t == 0) ? 0.0f : BIGV;
    rbuf[1][t] = BIGV;
    if (t == 0) { rbuf[0][TT] = BIGV; rbuf[1][TT] = BIGV; }
    __syncthreads();

    int p2 = 0, p1 = 1, pc = 2;
    float val = BIGV;
    for (int d = 2; d <= 2 * TT; ++d) {
        int j = d - t - 1;
        bool valid = (j >= 1) && (j <= TT);
        float cv = 0.0f;
        if (valid) {
            const float4* yr = (const float4*)(y + ((size_t)b * TT + (j - 1)) * CC);
#pragma unroll
            for (int q = 0; q < 16; ++q) {
                float4 yv = yr[q];
                float d0 = xr[q].x - yv.x, d1 = xr[q].y - yv.y;
                float d2 = xr[q].z - yv.z, d3 = xr[q].w - yv.w;
                cv += d0 * d0 + d1 * d1 + d2 * d2 + d3 * d3;
            }
        }
        float v = cv + softmin3(rbuf[p1][t], rbuf[p1][t + 1], rbuf[p2][t]);
        val = valid ? v : BIGV;
        rbuf[pc][t + 1] = val;
        if (t == 0) rbuf[pc][0] = BIGV;
        __syncthreads();
        int tmp = p2; p2 = p1; p1 = pc; pc = tmp;
    }
    if (t == TT - 1) atomicAdd(out, val);
}

extern "C" void kernel_launch(void* const* d_in, const int* in_sizes, int n_in,
                              void* d_out, int out_size, void* d_ws, size_t ws_size,
                              hipStream_t stream) {
    const float* x = (const float*)d_in[0];
    const float* y = (const float*)d_in[1];
    float* out = (float*)d_out;

    hipMemsetAsync(d_out, 0, sizeof(float) * out_size, stream);

    const size_t skew_b = (size_t)BB * NROWS * 64 * sizeof(float);   // 64 MiB
    const size_t bnd_b  = (size_t)BB * 16 * BNDROW * sizeof(float);  // 1.18 MB
    const size_t flag_b = (size_t)BB * 16 * 16 * sizeof(int);        // 16 KB

    if (ws_size >= skew_b + bnd_b + flag_b) {
        float* skew = (float*)d_ws;
        float* bndg = (float*)((char*)d_ws + skew_b);
        int* flags  = (int*)((char*)d_ws + skew_b + bnd_b);
        hipMemsetAsync(flags, 0, flag_b, stream);
        dim3 g1(16, 16, BB);
        skew_cost_kernel<<<g1, 256, 0, stream>>>(x, y, skew);
        dtw_pipe<<<256, 64, 0, stream>>>(skew, bndg, flags, out);
    } else if (ws_size >= skew_b) {
        float* skew = (float*)d_ws;
        dim3 g1(16, 16, BB);
        skew_cost_kernel<<<g1, 256, 0, stream>>>(x, y, skew);
        dtw_kernel<<<BB, 1024, 0, stream>>>(skew, out);
    } else {
        dtw_fly_kernel<<<BB, 1024, 0, stream>>>(x, y, out);
    }
}